// Round 11
// baseline (2057.198 us; speedup 1.0000x reference)
//
#include <hip/hip_runtime.h>
#include <cmath>

// Problem geometry (fixed by setup_inputs)
#define HH 160
#define WW 192
#define DD 160
#define WD (WW*DD)          // 30720
#define NPTS (HH*WW*DD)     // 4,915,200
#define NP4  (NPTS/4)
#define INV_WSZ (1.0f/729.0f)
#define ADAM_B1 0.9f
#define ADAM_B2 0.999f
#define ADAM_LR 0.1f
#define ADAM_EPS 1e-8f
#define NBLK_FINAL 4800     // NP4/256 exactly

// ---------------- persistent device-global scratch ----------------
// f32 streams that feed box filters / outputs; bf16 for Adam state + warp I,G
// (pure multiplicative factors — 0.4% rel error, output shift ~1e-4 vs 3.5e-3 thr).
__device__ __align__(16) float g_flowA[3*NPTS];
__device__ __align__(16) float g_flowB[3*NPTS];
__device__ __align__(16) float g_X   [3*NPTS];
__device__ __align__(16) float g_Y   [3*NPTS];
__device__ __align__(16) float g_uJ  [NPTS];
__device__ __align__(16) float g_Jv  [NPTS];
__device__ __align__(16) unsigned short g_m16[3*NPTS];   // Adam m   (bf16)
__device__ __align__(16) unsigned short g_v16[3*NPTS];   // Adam v   (bf16)
__device__ __align__(16) unsigned short g_w16[3*NPTS];   // Adam vhat(bf16)
__device__ __align__(16) unsigned short g_I16[NPTS];     // trilinear value (bf16)
__device__ __align__(16) unsigned short g_G16[3*NPTS];   // trilinear grads (bf16)
__device__ double g_part[8192];

// ---------------- helpers ----------------

typedef float nat4 __attribute__((ext_vector_type(4)));  // native clang vectors for NT builtins
typedef float nat2 __attribute__((ext_vector_type(2)));

__device__ __forceinline__ float4 ld4(const float* p) { return *reinterpret_cast<const float4*>(p); }
__device__ __forceinline__ void  st4(float* p, float4 v) { *reinterpret_cast<float4*>(p) = v; }
__device__ __forceinline__ float4 ld4nt(const float* p) {
    nat4 t = __builtin_nontemporal_load(reinterpret_cast<const nat4*>(p));
    return float4{t.x, t.y, t.z, t.w};
}
__device__ __forceinline__ void st4nt(float* p, float4 v) {
    nat4 t = {v.x, v.y, v.z, v.w};
    __builtin_nontemporal_store(t, reinterpret_cast<nat4*>(p));
}
#define UNPK(V,A) { A[0]=(V).x; A[1]=(V).y; A[2]=(V).z; A[3]=(V).w; }

// bf16 (RNE) pack/unpack, 4 elems = 8 B, NT
__device__ __forceinline__ unsigned short f2bf(float f) {
    unsigned u = __float_as_uint(f);
    u += 0x7FFFu + ((u >> 16) & 1u);
    return (unsigned short)(u >> 16);
}
__device__ __forceinline__ void ld4bf_nt(const unsigned short* p, float* A) {
    nat2 t = __builtin_nontemporal_load(reinterpret_cast<const nat2*>(p));
    unsigned a = __float_as_uint(t.x), b = __float_as_uint(t.y);
    A[0] = __uint_as_float(a << 16);
    A[1] = __uint_as_float(a & 0xFFFF0000u);
    A[2] = __uint_as_float(b << 16);
    A[3] = __uint_as_float(b & 0xFFFF0000u);
}
__device__ __forceinline__ void st4bf_nt(unsigned short* p, const float* A) {
    unsigned a = (unsigned)f2bf(A[0]) | ((unsigned)f2bf(A[1]) << 16);
    unsigned b = (unsigned)f2bf(A[2]) | ((unsigned)f2bf(A[3]) << 16);
    nat2 t; t.x = __uint_as_float(a); t.y = __uint_as_float(b);
    __builtin_nontemporal_store(t, reinterpret_cast<nat2*>(p));
}

__device__ __forceinline__ float fetchx(const float* __restrict__ x, int i, int j, int k) {
    if ((unsigned)i >= (unsigned)HH || (unsigned)j >= (unsigned)WW || (unsigned)k >= (unsigned)DD)
        return 0.0f;
    return x[(i*WW + j)*DD + k];
}

// 12-float window [idx-4, idx+8) with zero-padding at line edges (fp-exact clip).
__device__ __forceinline__ void load12(const float* base, int idx, int dp, float* t) {
    float4 a = (dp == 0)    ? float4{0,0,0,0} : ld4(base + idx - 4);
    float4 b = ld4(base + idx);
    float4 c = (dp == DD-4) ? float4{0,0,0,0} : ld4(base + idx + 4);
    t[0]=a.x; t[1]=a.y; t[2]=a.z; t[3]=a.w;
    t[4]=b.x; t[5]=b.y; t[6]=b.z; t[7]=b.w;
    t[8]=c.x; t[9]=c.y; t[10]=c.z; t[11]=c.w;
}

// ====== k1: fused warp + trilinear gradients + D-axis box of (I, I^2, I*J) ======
__global__ void __launch_bounds__(320) warp_momD_k(
        const float* __restrict__ x, const float* __restrict__ y,
        const float* __restrict__ finit, int fin_code)
{
    __shared__ __align__(16) float sI[8][168];   // 4 zero-pad front/back
    __shared__ __align__(16) float sJ[8][168];
    int tx = threadIdx.x;                 // 0..39
    int ty = threadIdx.y;                 // 0..7
    int line = blockIdx.x*8 + ty;         // h*WW + w
    int h = line / WW, w = line % WW;
    int dp = tx*4;
    int idx = line*DD + dp;
    const float* fin = (fin_code == 0) ? finit : ((fin_code == 1) ? g_flowA : g_flowB);

    float F0[4], F1[4], F2[4], Y4[4];
    { float4 a = ld4(fin + idx);          UNPK(a, F0); }
    { float4 a = ld4(fin + NPTS + idx);   UNPK(a, F1); }
    { float4 a = ld4(fin + 2*NPTS + idx); UNPK(a, F2); }
    { float4 a = ld4(y + idx);            UNPK(a, Y4); }

    float GX[4], GY[4], GZ[4], IV[4];
#pragma unroll
    for (int e = 0; e < 4; e++) {
        float c0 = (float)h + F0[e];
        float c1 = (float)w + F1[e];
        float c2 = (float)(dp + e) + F2[e];
        float fl0 = floorf(c0), fl1 = floorf(c1), fl2 = floorf(c2);
        int i0 = (int)fl0, j0 = (int)fl1, k0 = (int)fl2;
        float fx = c0 - fl0, fy = c1 - fl1, fz = c2 - fl2;
        float v000 = fetchx(x, i0,   j0,   k0  ), v001 = fetchx(x, i0,   j0,   k0+1);
        float v010 = fetchx(x, i0,   j0+1, k0  ), v011 = fetchx(x, i0,   j0+1, k0+1);
        float v100 = fetchx(x, i0+1, j0,   k0  ), v101 = fetchx(x, i0+1, j0,   k0+1);
        float v110 = fetchx(x, i0+1, j0+1, k0  ), v111 = fetchx(x, i0+1, j0+1, k0+1);
        float c00 = v000*(1.0f-fz) + v001*fz;
        float c01 = v010*(1.0f-fz) + v011*fz;
        float c10 = v100*(1.0f-fz) + v101*fz;
        float c11 = v110*(1.0f-fz) + v111*fz;
        float a0 = c00*(1.0f-fy) + c01*fy;
        float a1 = c10*(1.0f-fy) + c11*fy;
        float Ival = a0*(1.0f-fx) + a1*fx;
        IV[e] = Ival;
        sI[ty][4+dp+e] = Ival;
        sJ[ty][4+dp+e] = Y4[e];
        GX[e] = (1.0f-fy)*((v100-v000)*(1.0f-fz) + (v101-v001)*fz)
              +        fy*((v110-v010)*(1.0f-fz) + (v111-v011)*fz);
        GY[e] = (1.0f-fx)*((v010-v000)*(1.0f-fz) + (v011-v001)*fz)
              +        fx*((v110-v100)*(1.0f-fz) + (v111-v101)*fz);
        GZ[e] = (1.0f-fx)*((v001-v000)*(1.0f-fy) + (v011-v010)*fy)
              +        fx*((v101-v100)*(1.0f-fy) + (v111-v110)*fy);
    }
    st4bf_nt(g_I16 + idx,          IV);
    st4bf_nt(g_G16 + idx,          GX);
    st4bf_nt(g_G16 + NPTS + idx,   GY);
    st4bf_nt(g_G16 + 2*NPTS + idx, GZ);

    if (tx == 0) {
#pragma unroll
        for (int j = 0; j < 4; j++) { sI[ty][j] = 0.f; sJ[ty][j] = 0.f; }
    }
    if (tx == 39) {
#pragma unroll
        for (int j = 164; j < 168; j++) { sI[ty][j] = 0.f; sJ[ty][j] = 0.f; }
    }
    __syncthreads();

    float tI[12], tJ[12];
    { float4 a = ld4(&sI[ty][dp]);   UNPK(a, (&tI[0])); }
    { float4 a = ld4(&sI[ty][dp+4]); UNPK(a, (&tI[4])); }
    { float4 a = ld4(&sI[ty][dp+8]); UNPK(a, (&tI[8])); }
    { float4 a = ld4(&sJ[ty][dp]);   UNPK(a, (&tJ[0])); }
    { float4 a = ld4(&sJ[ty][dp+4]); UNPK(a, (&tJ[4])); }
    { float4 a = ld4(&sJ[ty][dp+8]); UNPK(a, (&tJ[8])); }

    float s1a[4], s2a[4], s3a[4];
#pragma unroll
    for (int e = 0; e < 4; e++) {
        float s1 = 0.f, s2 = 0.f, s3 = 0.f;
#pragma unroll
        for (int j = 0; j < 9; j++) {
            float a = tI[e+j], b = tJ[e+j];
            s1 += a; s2 += a*a; s3 += a*b;
        }
        s1a[e] = s1; s2a[e] = s2; s3a[e] = s3;
    }
    st4nt(g_X + idx,          float4{s1a[0],s1a[1],s1a[2],s1a[3]});
    st4nt(g_X + NPTS + idx,   float4{s2a[0],s2a[1],s2a[2],s2a[3]});
    st4nt(g_X + 2*NPTS + idx, float4{s3a[0],s3a[1],s3a[2],s3a[3]});
}

// ================= k2/k4: W-axis box via LDS plane tile (g_X -> g_Y) =================
template<int NF>
__global__ void __launch_bounds__(256) boxW_k()
{
    __shared__ __align__(16) float s[WW][32];
    int h  = blockIdx.x;
    int d0 = blockIdx.y*32;
    int t  = threadIdx.x;
#pragma unroll
    for (int f = 0; f < NF; f++) {
        const float* base = g_X + f*NPTS + h*WD + d0;
        for (int q = t; q < WW*8; q += 256) {
            int wq = q >> 3, dq = (q & 7)*4;
            st4(&s[wq][dq], ld4nt(base + wq*DD + dq));
        }
        __syncthreads();
        float* ob = g_Y + f*NPTS + h*WD + d0;
        for (int q = t; q < WW*8; q += 256) {
            int wq = q >> 3, dq = (q & 7)*4;
            int lo = (wq < 4) ? -wq : -4;
            int hi = (wq > WW-5) ? (WW-1-wq) : 4;
            float4 acc = float4{0,0,0,0};
            for (int k = lo; k <= hi; k++) {
                float4 v = ld4(&s[wq+k][dq]);
                acc.x += v.x; acc.y += v.y; acc.z += v.z; acc.w += v.w;
            }
            st4nt(ob + wq*DD + dq, acc);
        }
        __syncthreads();
    }
}

// ======= k3: H-box(moments) + fields + H-box(fields) (g_Y -> g_X) =======
__global__ void __launch_bounds__(256) boxH_fields_k()
{
    __shared__ __align__(16) float sf[3][HH][16];
    int w  = blockIdx.x;
    int d0 = blockIdx.y*16;
    int t  = threadIdx.x;

    // Phase A: H-box each moment field straight from global (L1 reuse on taps)
#pragma unroll
    for (int f = 0; f < 3; f++) {
        const float* base = g_Y + f*NPTS + w*DD + d0;
        for (int q = t; q < HH*4; q += 256) {
            int hh = q >> 2, dq = (q & 3)*4;
            int lo = (hh < 4) ? -hh : -4;
            int hi = (hh > HH-5) ? (HH-1-hh) : 4;
            float4 acc = float4{0,0,0,0};
            for (int k = lo; k <= hi; k++) {
                float4 v = ld4(base + (hh+k)*WD + dq);
                acc.x += v.x; acc.y += v.y; acc.z += v.z; acc.w += v.w;
            }
            st4(&sf[f][hh][dq], acc);
        }
    }
    __syncthreads();

    // Phase B: pointwise fields A,B,C — compute all, sync, then overwrite.
    // q-loop runs up to 3 iterations (HH*4=640 / 256) -> arrays sized [3][4].
    {
        float A_[3][4], B_[3][4], C_[3][4];
        int qi = 0;
        for (int q = t; q < HH*4; q += 256, qi++) {
            int hh = q >> 2, dq = (q & 3)*4;
            int idxg = hh*WD + w*DD + d0 + dq;
            float Is[4], I2s[4], IJs[4], UJ[4], JV[4];
            { float4 a = ld4(&sf[0][hh][dq]); UNPK(a, Is); }
            { float4 a = ld4(&sf[1][hh][dq]); UNPK(a, I2s); }
            { float4 a = ld4(&sf[2][hh][dq]); UNPK(a, IJs); }
            { float4 a = ld4(g_uJ + idxg);    UNPK(a, UJ); }
            { float4 a = ld4(g_Jv + idxg);    UNPK(a, JV); }
#pragma unroll
            for (int e = 0; e < 4; e++) {
                float uI = Is[e] * INV_WSZ;
                float cross = IJs[e] - UJ[e]*Is[e];
                float Ivar  = I2s[e] - uI*Is[e];
                float den = Ivar*JV[e] + 1e-5f;
                float inv = 1.0f / den;
                float A = 2.0f*cross*inv;
                float B = -cross*cross*JV[e]*inv*inv;
                A_[qi][e] = A; B_[qi][e] = B; C_[qi][e] = A*UJ[e] + 2.0f*B*uI;
            }
        }
        __syncthreads();
        qi = 0;
        for (int q = t; q < HH*4; q += 256, qi++) {
            int hh = q >> 2, dq = (q & 3)*4;
            st4(&sf[0][hh][dq], float4{A_[qi][0],A_[qi][1],A_[qi][2],A_[qi][3]});
            st4(&sf[1][hh][dq], float4{B_[qi][0],B_[qi][1],B_[qi][2],B_[qi][3]});
            st4(&sf[2][hh][dq], float4{C_[qi][0],C_[qi][1],C_[qi][2],C_[qi][3]});
        }
    }
    __syncthreads();

    // Phase C: H-box the fields -> g_X
#pragma unroll
    for (int f = 0; f < 3; f++) {
        float* ob = g_X + f*NPTS + w*DD + d0;
        for (int q = t; q < HH*4; q += 256) {
            int hh = q >> 2, dq = (q & 3)*4;
            int lo = (hh < 4) ? -hh : -4;
            int hi = (hh > HH-5) ? (HH-1-hh) : 4;
            float4 acc = float4{0,0,0,0};
            for (int k = lo; k <= hi; k++) {
                float4 v = ld4(&sf[f][hh+k][dq]);
                acc.x += v.x; acc.y += v.y; acc.z += v.z; acc.w += v.w;
            }
            st4nt(ob + hh*WD + dq, acc);
        }
    }
}

// ===== k5: inline D-box + (bf16 I, gx,gy,gz) + reg + Adam (bf16 state) =====
template<bool FINAL>
__global__ void __launch_bounds__(256) grad_adam_k(
        const float* __restrict__ y,
        const float* __restrict__ finit,
        int fin_code, int fout_code,
        float inv_bc1, float inv_sqrt_bc2, int is_first)
{
    __shared__ double sd[256];
    int p = blockIdx.x*blockDim.x + threadIdx.x;   // pack of 4 voxels along d
    if (p >= NP4) return;
    int line = p / (DD/4);
    int dp   = (p % (DD/4))*4;
    int idx  = line*DD + dp;
    int w = line % WW;
    int h = line / WW;
    const float* fin = (fin_code == 0) ? finit : ((fin_code == 1) ? g_flowA : g_flowB);
    float* fout = (fout_code == 1) ? g_flowA : g_flowB;

    // ---- D-box of the H,W-boxed fields (12-float window, zero-padded) ----
    float SA[4], SB[4], SC[4];
    {
        float t[12];
        load12(g_Y,          idx, dp, t);
#pragma unroll
        for (int e = 0; e < 4; e++) { float s=0.f;
#pragma unroll
            for (int j = 0; j < 9; j++) s += t[e+j]; SA[e]=s; }
        load12(g_Y + NPTS,   idx, dp, t);
#pragma unroll
        for (int e = 0; e < 4; e++) { float s=0.f;
#pragma unroll
            for (int j = 0; j < 9; j++) s += t[e+j]; SB[e]=s; }
        load12(g_Y + 2*NPTS, idx, dp, t);
#pragma unroll
        for (int e = 0; e < 4; e++) { float s=0.f;
#pragma unroll
            for (int j = 0; j < 9; j++) s += t[e+j]; SC[e]=s; }
    }

    float F[3][4];
    { float4 a = ld4(fin + idx);          UNPK(a, F[0]); }
    { float4 a = ld4(fin + NPTS + idx);   UNPK(a, F[1]); }
    { float4 a = ld4(fin + 2*NPTS + idx); UNPK(a, F[2]); }
    float Y4[4], I4[4], GX[4], GY[4], GZ[4];
    { float4 a = ld4(y + idx);            UNPK(a, Y4); }
    ld4bf_nt(g_I16 + idx,          I4);
    ld4bf_nt(g_G16 + idx,          GX);
    ld4bf_nt(g_G16 + NPTS + idx,   GY);
    ld4bf_nt(g_G16 + 2*NPTS + idx, GZ);

    float GS[3][4];
#pragma unroll
    for (int e = 0; e < 4; e++) {
        float gI = -(1.0f/(float)NPTS) * (Y4[e]*SA[e] + 2.0f*I4[e]*SB[e] - SC[e]);
        GS[0][e] = gI*GX[e]; GS[1][e] = gI*GY[e]; GS[2][e] = gI*GZ[e];
    }

    const float coefH = 2.0f / (3.0f * (float)(3*(HH-1)*WW*DD));
    const float coefW = 2.0f / (3.0f * (float)(3*HH*(WW-1)*DD));
    const float coefD = 2.0f / (3.0f * (float)(3*HH*WW*(DD-1)));

    double msea = 0.0;

#pragma unroll
    for (int c = 0; c < 3; c++) {
        const float* fc = fin + c*NPTS;
        int o = c*NPTS + idx;
        float FU[4], FD[4], FL[4], FR[4];
        { float4 a = (h > 0)    ? ld4(fc + idx - WD) : float4{0,0,0,0}; UNPK(a, FU); }
        { float4 a = (h < HH-1) ? ld4(fc + idx + WD) : float4{0,0,0,0}; UNPK(a, FD); }
        { float4 a = (w > 0)    ? ld4(fc + idx - DD) : float4{0,0,0,0}; UNPK(a, FL); }
        { float4 a = (w < WW-1) ? ld4(fc + idx + DD) : float4{0,0,0,0}; UNPK(a, FR); }
        float dl = (dp > 0)     ? fc[idx - 1] : 0.f;
        float dr = (dp < DD-4)  ? fc[idx + 4] : 0.f;

        float M[4], V[4], VH[4];
        if (is_first) {
#pragma unroll
            for (int e = 0; e < 4; e++) { M[e]=0.f; V[e]=0.f; VH[e]=0.f; }
        } else {
            ld4bf_nt(g_m16 + o, M);
            ld4bf_nt(g_v16 + o, V);
            ld4bf_nt(g_w16 + o, VH);
        }

        float FI[4];
        if (FINAL) { float4 a = ld4(finit + o); UNPK(a, FI); }

        float O[4];
#pragma unroll
        for (int e = 0; e < 4; e++) {
            int d = dp + e;
            float f0 = F[c][e];
            float r = 0.0f;
            if (h > 0)     r += coefH*(f0 - FU[e]);
            if (h < HH-1)  r -= coefH*(FD[e] - f0);
            if (w > 0)     r += coefW*(f0 - FL[e]);
            if (w < WW-1)  r -= coefW*(FR[e] - f0);
            float left  = (e == 0) ? dl : F[c][e-1];
            float right = (e == 3) ? dr : F[c][e+1];
            if (d > 0)     r += coefD*(f0 - left);
            if (d < DD-1)  r -= coefD*(right - f0);
            float g = GS[c][e] + r;

            float mm  = ADAM_B1*M[e]  + (1.0f - ADAM_B1)*g;
            float vv  = ADAM_B2*V[e]  + (1.0f - ADAM_B2)*g*g;
            float vhh = fmaxf(VH[e], vv);
            M[e] = mm; V[e] = vv; VH[e] = vhh;
            float den = sqrtf(vhh)*inv_sqrt_bc2 + ADAM_EPS;
            O[e] = f0 - ADAM_LR*(mm*inv_bc1)/den;
            if (FINAL) {
                float df = O[e] - FI[e];
                msea += (double)df * (double)df;
            }
        }
        if (!FINAL) {
            st4bf_nt(g_m16 + o, M);
            st4bf_nt(g_v16 + o, V);
            st4bf_nt(g_w16 + o, VH);
            st4(fout + o, float4{O[0],O[1],O[2],O[3]});
        }
    }

    if (FINAL) {
        int tid = threadIdx.x;
        sd[tid] = msea; __syncthreads();
        for (int o2 = 128; o2 > 0; o2 >>= 1) {
            if (tid < o2) sd[tid] += sd[tid + o2];
            __syncthreads();
        }
        if (tid == 0) g_part[blockIdx.x] = sd[0];
    }
}

// ================= pre-loop J stats =================

__global__ void jmomD_k(const float* __restrict__ J)
{
    __shared__ float sJ[2][DD];
    int tx = threadIdx.x, ty = threadIdx.y;
    int line = blockIdx.x*2 + ty;
    int idx = line*DD + tx;
    sJ[ty][tx] = J[idx];
    __syncthreads();
    int lo = (tx < 4) ? -tx : -4;
    int hi = (tx > DD-5) ? (DD-1-tx) : 4;
    float s1 = 0.f, s2 = 0.f;
    for (int k = lo; k <= hi; k++) {
        float b = sJ[ty][tx+k];
        s1 += b; s2 += b*b;
    }
    g_X[idx] = s1; g_X[NPTS + idx] = s2;
}

__global__ void __launch_bounds__(256) boxH2_jstats_k()
{
    int p = blockIdx.x*blockDim.x + threadIdx.x;
    if (p >= NP4) return;
    int idx = p*4;
    int h = idx / WD;
    int lo = (h < 4) ? -h : -4;
    int hi = (h > HH-5) ? (HH-1-h) : 4;
    float4 s1 = float4{0,0,0,0}, s2 = float4{0,0,0,0};
    for (int k = lo; k <= hi; k++) {
        float4 a = ld4(g_Y + idx + k*WD);
        float4 b = ld4(g_Y + NPTS + idx + k*WD);
        s1.x += a.x; s1.y += a.y; s1.z += a.z; s1.w += a.w;
        s2.x += b.x; s2.y += b.y; s2.z += b.z; s2.w += b.w;
    }
    float4 u  = float4{s1.x*INV_WSZ, s1.y*INV_WSZ, s1.z*INV_WSZ, s1.w*INV_WSZ};
    float4 jv = float4{s2.x - u.x*s1.x, s2.y - u.y*s1.y, s2.z - u.z*s1.z, s2.w - u.w*s1.w};
    st4(g_uJ + idx, u);
    st4(g_Jv + idx, jv);
}

// ================= final MSE fold =================

__global__ void mse_final_k(int nblk, float* __restrict__ out)
{
    __shared__ double sd[256];
    int tid = threadIdx.x;
    double s = 0.0;
    for (int i = tid; i < nblk; i += 256) s += g_part[i];
    sd[tid] = s; __syncthreads();
    for (int o = 128; o > 0; o >>= 1) {
        if (tid < o) sd[tid] += sd[tid + o];
        __syncthreads();
    }
    if (tid == 0) out[0] = (float)(sd[0] / (3.0*(double)NPTS));
}

// ================= launch =================

extern "C" void kernel_launch(void* const* d_in, const int* in_sizes, int n_in,
                              void* d_out, int out_size, void* d_ws, size_t ws_size,
                              hipStream_t stream)
{
    const float* x    = (const float*)d_in[0];
    const float* y    = (const float*)d_in[1];
    const float* finit= (const float*)d_in[2];
    (void)d_ws; (void)ws_size;

    dim3 blk(256);
    dim3 grd4((NP4 + 255)/256);           // 4800 blocks exactly
    dim3 lineBlk(DD, 2);
    dim3 lineGrd(HH*WW/2);
    dim3 wBlk(256);
    dim3 wGrd(HH, DD/32);
    dim3 hGrd(WW, DD/16);
    dim3 wmBlk(40, 8);
    dim3 wmGrd(HH*WW/8);

    // J-side stats (flow-independent)
    jmomD_k<<<lineGrd, lineBlk, 0, stream>>>(y);
    boxW_k<2><<<wGrd, wBlk, 0, stream>>>();            // X -> Y (W)
    boxH2_jstats_k<<<grd4, blk, 0, stream>>>();        // Y -> uJ, Jv (H inline)

    // fin/fout codes: 0 = finit, 1 = g_flowA, 2 = g_flowB
    int fin_code = 0, fout_code = 1;
    for (int t = 1; t <= 5; t++) {
        warp_momD_k<<<wmGrd, wmBlk, 0, stream>>>(x, y, finit, fin_code); // -> X, g_I16, g_G16
        boxW_k<3><<<wGrd, wBlk, 0, stream>>>();                          // X -> Y (W)
        boxH_fields_k<<<hGrd, blk, 0, stream>>>();                       // Y -> X (H, fields, H)
        boxW_k<3><<<wGrd, wBlk, 0, stream>>>();                          // X -> Y (W)
        double bc1 = 1.0 - pow(0.9, (double)t);
        double bc2 = 1.0 - pow(0.999, (double)t);
        if (t < 5) {
            grad_adam_k<false><<<grd4, blk, 0, stream>>>(y, finit, fin_code, fout_code,
                                                         (float)(1.0/bc1), (float)(1.0/sqrt(bc2)),
                                                         (t == 1) ? 1 : 0);
        } else {
            grad_adam_k<true><<<grd4, blk, 0, stream>>>(y, finit, fin_code, fout_code,
                                                        (float)(1.0/bc1), (float)(1.0/sqrt(bc2)), 0);
        }
        fin_code = fout_code;
        fout_code = (fout_code == 1) ? 2 : 1;
    }

    mse_final_k<<<1, blk, 0, stream>>>(NBLK_FINAL, (float*)d_out);
}